// Round 7
// baseline (6323.233 us; speedup 1.0000x reference)
//
#include <hip/hip_runtime.h>

typedef _Float16 f16;
typedef _Float16 half8 __attribute__((ext_vector_type(8)));
typedef float f32x4 __attribute__((ext_vector_type(4)));
typedef unsigned int u32;
typedef u32 u32x2 __attribute__((ext_vector_type(2)));
typedef u32 u32x4 __attribute__((ext_vector_type(4)));

__device__ inline float frcp(float x) {
#if __has_builtin(__builtin_amdgcn_rcpf)
  return __builtin_amdgcn_rcpf(x);
#else
  return 1.0f / x;
#endif
}
__device__ inline float fexp2(float x) {
#if __has_builtin(__builtin_amdgcn_exp2f)
  return __builtin_amdgcn_exp2f(x);
#else
  return exp2f(x);
#endif
}

// ---------------- small prep kernels ----------------

__global__ void k_cvt(const float* __restrict__ s, f16* __restrict__ d, int n) {
  int i = blockIdx.x * 256 + threadIdx.x;
  if (i < n) d[i] = (f16)s[i];
}

__global__ void k_zero(u32* __restrict__ p, int n) {
  int i = blockIdx.x * 256 + threadIdx.x;
  if (i < n) p[i] = 0u;
}

__global__ void k_w0pad(const float* __restrict__ w0, f16* __restrict__ d) {
  int i = blockIdx.x * 256 + threadIdx.x;
  if (i >= 1024 * 96) return;
  int row = i / 96, c = i % 96;
  d[i] = (c < 89) ? (f16)w0[row * 89 + c] : (f16)0.f;
}

__global__ void k_xb0(const float* __restrict__ x, f16* __restrict__ d) {
  int i = blockIdx.x * 256 + threadIdx.x;
  if (i >= 128 * 500 * 96) return;
  int f = i % 96;
  int t = (i / 96) % 500;
  int s = i / (96 * 500);
  float v = 0.f;
  if (f < 89) {
    if (s < 64) v = x[((size_t)s * 500 + t) * 89 + f];
    else        v = x[((size_t)(s - 64) * 500 + (499 - t)) * 89 + f];
  }
  d[i] = (f16)v;
}

__global__ void k_offs(const int* __restrict__ lens, int* __restrict__ offs) {
  if (threadIdx.x == 0 && blockIdx.x == 0) {
    int s = 0;
    for (int i = 0; i < 64; ++i) { offs[i] = s; s += lens[i]; }
  }
}

// ---------------- gates GEMM ----------------
// Writes gates in k_rec's FRAG-MAJOR layout:
// f16 idx = (t>>2)*524288 + sg*65536 + cg*8192 + w*2048 + lane*32 + (t&3)*8 + az*4 + r
// where m = sg*16 + (lane>>4)*4 + r, n = az*512 + cg*64 + w*16 + (lane&15).
template <int MODE>
__global__ __launch_bounds__(256) void k_gates(const f16* __restrict__ Aw,
                                               const f16* __restrict__ W16,
                                               const float* __restrict__ bias,
                                               f16* __restrict__ gates) {
  constexpr int KW = MODE ? 1024 : 96;
  const int t = blockIdx.x;
  const int nb = blockIdx.y * 128;
  const int tid = threadIdx.x;
  const int w = tid >> 6, l = tid & 63, c = l & 15, rg = l >> 4;
  const int wr = w >> 1, wc = w & 1;

  __shared__ f16 As[128 * 32];
  __shared__ f16 Bs[128 * 32];

  f32x4 acc[4][4] = {};

  const int srow = tid >> 1;
  const int seg = (tid & 1) * 16;
  const int ch0 = seg >> 3;
  const int wsw = (srow >> 1) & 3;

  for (int kb = 0; kb < KW; kb += 32) {
    const f16* pa;
    if (MODE == 0) {
      pa = Aw + ((size_t)srow * 500 + t) * 96 + kb + seg;
    } else {
      int f0 = kb + seg;
      int half = f0 >> 9;
      int col = f0 & 511;
      int s = srow;
      int seq, time;
      if (s < 64) { seq = half ? 64 + s : s;  time = half ? 499 - t : t; }
      else        { seq = half ? s : s - 64;  time = half ? t : 499 - t; }
      pa = Aw + ((size_t)seq * 500 + time) * 512 + col;
    }
    const f16* pb = W16 + (size_t)(nb + srow) * KW + kb + seg;
    half8 a0 = *(const half8*)pa;
    half8 a1 = *(const half8*)(pa + 8);
    half8 b0 = *(const half8*)pb;
    half8 b1 = *(const half8*)(pb + 8);
    __syncthreads();
    *(half8*)&As[srow * 32 + ((ch0 + 0) ^ wsw) * 8] = a0;
    *(half8*)&As[srow * 32 + ((ch0 + 1) ^ wsw) * 8] = a1;
    *(half8*)&Bs[srow * 32 + ((ch0 + 0) ^ wsw) * 8] = b0;
    *(half8*)&Bs[srow * 32 + ((ch0 + 1) ^ wsw) * 8] = b1;
    __syncthreads();
    half8 aF[4], bF[4];
#pragma unroll
    for (int i = 0; i < 4; ++i) {
      int row = wr * 64 + i * 16 + c;
      aF[i] = *(const half8*)&As[row * 32 + ((rg ^ ((row >> 1) & 3)) * 8)];
    }
#pragma unroll
    for (int j = 0; j < 4; ++j) {
      int row = wc * 64 + j * 16 + c;
      bF[j] = *(const half8*)&Bs[row * 32 + ((rg ^ ((row >> 1) & 3)) * 8)];
    }
#pragma unroll
    for (int i = 0; i < 4; ++i)
#pragma unroll
      for (int j = 0; j < 4; ++j)
        acc[i][j] = __builtin_amdgcn_mfma_f32_16x16x32_f16(aF[i], bF[j], acc[i][j], 0, 0, 0);
  }

  const int tq = t >> 2, ts = t & 3;
#pragma unroll
  for (int j = 0; j < 4; ++j) {
    int n = nb + wc * 64 + j * 16 + c;
    float bj = bias[n];
    int az = n >> 9, nn = n & 511;
    int cg2 = nn >> 6, w2 = (nn >> 4) & 3, c2 = nn & 15;
#pragma unroll
    for (int i = 0; i < 4; ++i) {
#pragma unroll
      for (int r = 0; r < 4; ++r) {
        int m = wr * 64 + i * 16 + rg * 4 + r;
        int sg2 = m >> 4, sr = m & 15;
        int l2 = (sr >> 2) * 16 + c2;
        size_t off = (size_t)tq * 524288 + (size_t)sg2 * 65536 + (size_t)cg2 * 8192 +
                     (size_t)w2 * 2048 + (size_t)l2 * 32 + ts * 8 + az * 4 + (sr & 3);
        gates[off] = (f16)(acc[i][j][r] + bj);
      }
    }
  }
}

// ---------------- recurrence ----------------
// 64 WGs = 8 seq-groups x 8 col-groups. U (128 KB/WG) lives in LDS for all 500
// steps (r4: VGPR pin unfixable -> structural fix). h exchanged frag-major via
// hx[2][8][8192] f16 using the r4-PROVEN system-scope protocol (sc0 sc1 data,
// agent-scope atomic flags; MALL is the coherence point). r6's XCD-pure L2-scope
// variant raced (absmax 0.36) and is removed.
__global__ __launch_bounds__(256, 1) void k_rec(const f16* __restrict__ gates,
                                                const f16* __restrict__ U,
                                                f16* __restrict__ hs,
                                                f16* __restrict__ hx,
                                                u32* __restrict__ flags,
                                                int tagbase) {
  extern __shared__ f16 smem[];            // [65536 U][8192 h][1536 scratch]
  f16* ulds = smem;
  f16* hlds = smem + 65536;
  f16* scrb = smem + 65536 + 8192;

  const int bid = blockIdx.x;
  const int sg = bid & 7, cg = bid >> 3;
  const int tid = threadIdx.x;
  const int l = tid & 63, w = tid >> 6, c = l & 15, rg = l >> 4;
  const int s0 = sg * 16;

  // ---- stage U into LDS, once (layout verified r5/r6 derivation) ----
  {
    const f16* Ua = U + (size_t)cg * 64 * 512;
    const f16* Uz = U + (size_t)(512 + cg * 64) * 512;
#pragma unroll
    for (int it = 0; it < 16; ++it) {
      int rr = (it & 3) * 16 + c;                    // row in 64-row block
      int chunk = (it >> 2) * 16 + w * 4 + rg;       // col/8
      int col = chunk * 8;
      half8 va = *(const half8*)(Ua + (size_t)rr * 512 + col);
      half8 vz = *(const half8*)(Uz + (size_t)rr * 512 + col);
      int wv = rr >> 4, cc = rr & 15, kt = col >> 5, rg2 = (col >> 3) & 3;
      int base = (wv * 32 + kt) * 512 + (rg2 * 16 + cc) * 8;
      *(half8*)&ulds[base] = va;
      *(half8*)&ulds[base + 8192] = vz;
    }
  }
  __syncthreads();                          // U staged before any MFMA reads

  // producer-side constants
  const int ktp = cg * 2 + (w >> 1);
  const int pbase = ktp * 512 + (w & 1) * 256;
  f16* scr = scrb + w * 384;                 // 16 rows x stride 20 f16
  const int srow2 = (l >> 1) & 15;
  const int col2 = ktp * 32 + ((w & 1) * 2 + (l >> 5)) * 8 + (l & 1) * 4;
  const size_t tileoff = (size_t)sg * 8192;
  const u32* flbase = flags + sg * 32;
  u32* myflag = flags + sg * 32 + cg * 4 + w;

  // gates: 4-step batches, 16B/thread/step
  const f16* gbase = gates + (size_t)sg * 65536 + (size_t)cg * 8192 +
                     (size_t)w * 2048 + (size_t)l * 32;
  u32x4 gcur[4], gnxt[4];
#pragma unroll
  for (int q = 0; q < 4; ++q) gcur[q] = *(const u32x4*)(gbase + q * 8);

  float hold[4] = {0.f, 0.f, 0.f, 0.f};

  for (int tb = 0; tb < 125; ++tb) {
#pragma unroll
    for (int ts = 0; ts < 4; ++ts) {
      const int t = tb * 4 + ts;
      u32x4 d0, d1, d2, d3;
      if (t == 0) {
        d0 = (u32x4){0u, 0u, 0u, 0u}; d1 = d0; d2 = d0; d3 = d0;
      } else {
        // poll per-wave flags: 1 dword/lane, one 128B line per sg (r4-proven)
        const u32 tgt = (u32)(tagbase + t);
        const u32* fl = flbase + (l & 31);
        int g2 = 0;
        for (;;) {
          u32 f = __hip_atomic_load(fl, __ATOMIC_RELAXED, __HIP_MEMORY_SCOPE_AGENT);
          if (__all((int)(f >= tgt))) break;
          if (++g2 > (1 << 15)) break;  // safety valve
        }
        const f16* src = hx + (size_t)(t & 1) * 65536 + tileoff + (size_t)tid * 32;
        asm volatile("global_load_dwordx4 %0, %1, off sc0 sc1" : "=v"(d0) : "v"(src) : "memory");
        asm volatile("global_load_dwordx4 %0, %1, off sc0 sc1" : "=v"(d1) : "v"(src + 8) : "memory");
        asm volatile("global_load_dwordx4 %0, %1, off sc0 sc1" : "=v"(d2) : "v"(src + 16) : "memory");
        asm volatile("global_load_dwordx4 %0, %1, off sc0 sc1" : "=v"(d3) : "v"(src + 24) : "memory");
        asm volatile("s_waitcnt vmcnt(0)"
                     : "+v"(d0), "+v"(d1), "+v"(d2), "+v"(d3) : : "memory");
      }

      // gate batch for next tb (issued outside the drain window)
      if (ts == 0) {
        int tqn = (tb < 124) ? tb + 1 : 124;
        const f16* gb2 = gbase + (size_t)tqn * 524288;
#pragma unroll
        for (int q = 0; q < 4; ++q) gnxt[q] = *(const u32x4*)(gb2 + q * 8);
      }

      // stage h -> LDS (linear, conflict-free)
      *(u32x4*)&hlds[tid * 32 + 0]  = d0;
      *(u32x4*)&hlds[tid * 32 + 8]  = d1;
      *(u32x4*)&hlds[tid * 32 + 16] = d2;
      *(u32x4*)&hlds[tid * 32 + 24] = d3;
      __syncthreads();

      // MFMA: acc = gates + h @ U^T, B-frags from LDS
      f32x4 acc_a, acc_z;
      const half8 gv = __builtin_bit_cast(half8, gcur[ts]);
#pragma unroll
      for (int r = 0; r < 4; ++r) { acc_a[r] = (float)gv[r]; acc_z[r] = (float)gv[4 + r]; }
#pragma unroll
      for (int kt = 0; kt < 16; ++kt) {
        half8 aF = *(const half8*)&hlds[kt * 512 + l * 8];
        half8 bA = *(const half8*)&ulds[(w * 32 + kt) * 512 + l * 8];
        half8 bZ = *(const half8*)&ulds[(w * 32 + 16 + kt) * 512 + l * 8];
        acc_a = __builtin_amdgcn_mfma_f32_16x16x32_f16(aF, bA, acc_a, 0, 0, 0);
        acc_z = __builtin_amdgcn_mfma_f32_16x16x32_f16(aF, bZ, acc_z, 0, 0, 0);
      }
      __syncthreads();

      // gating (lane-local; C layout col=c, row=rg*4+r) -> frag-order shuffle
#pragma unroll
      for (int r = 0; r < 4; ++r) {
        float av = acc_a[r];
        float zv = acc_z[r];
        float zs = frcp(1.f + fexp2(-1.44269504f * zv));   // sigmoid(z)
        float u2 = fexp2(2.88539008f * av);
        float th = 1.f - 2.f * frcp(u2 + 1.f);             // tanh(a)
        float hn = th + zs * (hold[r] - th);
        hold[r] = hn;
        scr[(rg * 4 + r) * 20 + c] = (f16)hn;
      }
      u32x2 pkt = *(const u32x2*)&scr[srow2 * 20 + (l >> 5) * 8 + (l & 1) * 4];

      f16* dst = hx + (size_t)((t + 1) & 1) * 65536 + tileoff + pbase + (size_t)l * 4;
      const u32 tg2 = (u32)(tagbase + t + 1);
      asm volatile("global_store_dwordx2 %0, %1, off sc0 sc1" :: "v"(dst), "v"(pkt) : "memory");
      asm volatile("s_waitcnt vmcnt(0)" ::: "memory");
      if (l == 0)
        __hip_atomic_store(myflag, tg2, __ATOMIC_RELAXED, __HIP_MEMORY_SCOPE_AGENT);

      // hs output (off protocol path)
      *(u32x2*)&hs[((size_t)(s0 + srow2) * 500 + t) * 512 + col2] = pkt;
    }
#pragma unroll
    for (int q = 0; q < 4; ++q) gcur[q] = gnxt[q];
  }
}

// ---------------- FC + pack ----------------
__global__ __launch_bounds__(256) void k_fc(const f16* __restrict__ hs,
                                            const f16* __restrict__ wfc,
                                            const float* __restrict__ bfc,
                                            const int* __restrict__ lens,
                                            const int* __restrict__ offs,
                                            float* __restrict__ out) {
  const int b = blockIdx.x, chunk = blockIdx.y;
  const int tid = threadIdx.x;
  __shared__ f16 X[16][1032];
#pragma unroll
  for (int ii = 0; ii < 8; ++ii) {
    int sg = ii * 256 + tid;
    int row = sg >> 7;
    int f = (sg & 127) * 8;
    int t = chunk * 16 + row;
    int tt = t < 500 ? t : 499;
    int half = f >> 9, col = f & 511;
    int seq = half ? 64 + b : b;
    int time = half ? 499 - tt : tt;
    *(half8*)&X[row][f] = *(const half8*)&hs[((size_t)seq * 500 + time) * 512 + col];
  }
  __syncthreads();
  int row = tid >> 4, og = tid & 15;
  int t = chunk * 16 + row;
  int len = lens[b];
  float acc[5];
#pragma unroll
  for (int j = 0; j < 5; ++j) {
    int o = j * 16 + og;
    acc[j] = (o < 72) ? bfc[o] : 0.f;
  }
  for (int k8 = 0; k8 < 128; ++k8) {
    half8 x8 = *(const half8*)&X[row][k8 * 8];
    float xf[8];
#pragma unroll
    for (int e = 0; e < 8; ++e) xf[e] = (float)x8[e];
#pragma unroll
    for (int j = 0; j < 5; ++j) {
      int o = j * 16 + og;
      int oc = o < 72 ? o : 0;
      half8 w8 = *(const half8*)&wfc[(size_t)oc * 1024 + k8 * 8];
#pragma unroll
      for (int e = 0; e < 8; ++e) acc[j] += xf[e] * (float)w8[e];
    }
  }
  if (t < 500 && t < len) {
    size_t base = ((size_t)offs[b] + t) * 72;
#pragma unroll
    for (int j = 0; j < 5; ++j) {
      int o = j * 16 + og;
      if (o < 72) out[base + o] = acc[j];
    }
  }
}

// ---------------- launcher ----------------

extern "C" void kernel_launch(void* const* d_in, const int* in_sizes, int n_in,
                              void* d_out, int out_size, void* d_ws, size_t ws_size,
                              hipStream_t stream) {
  const float* batch = (const float*)d_in[0];
  const int*   lens  = (const int*)d_in[1];
  const float* w0 = (const float*)d_in[2];
  const float* b0 = (const float*)d_in[3];
  const float* u0 = (const float*)d_in[4];
  const float* w1 = (const float*)d_in[5];
  const float* b1 = (const float*)d_in[6];
  const float* u1 = (const float*)d_in[7];
  const float* w2 = (const float*)d_in[8];
  const float* b2 = (const float*)d_in[9];
  const float* u2 = (const float*)d_in[10];
  const float* wfc = (const float*)d_in[11];
  const float* bfc = (const float*)d_in[12];
  float* out = (float*)d_out;

  char* ws = (char*)d_ws;
  const size_t GATES_OFF = 0;                  // [125][8][8][4][64][4][8] f16 = 131,072,000
  const size_t HS_OFF    = 131072000;          // [128][500][512]  f16 =  65,536,000
  const size_t XB0_OFF   = 196608000;          // [128][500][96]   f16 =  12,288,000
  const size_t W0P_OFF   = 208896000;
  const size_t W1_OFF    = 209092608;
  const size_t W2_OFF    = 211189760;
  const size_t U0_OFF    = 213286912;
  const size_t U1_OFF    = 214335488;
  const size_t U2_OFF    = 215384064;
  const size_t WFC_OFF   = 216432640;
  const size_t OFFS_OFF  = 216580096;
  const size_t HX_OFF    = 216581120;          // [2][8][8192] f16 = 262,144 B
  const size_t FLAGS_OFF = 216843264;          // [8][32] u32 = 1024 B

  f16* g_gates = (f16*)(ws + GATES_OFF);
  f16* g_hs    = (f16*)(ws + HS_OFF);
  f16* g_xb0   = (f16*)(ws + XB0_OFF);
  f16* g_w0p   = (f16*)(ws + W0P_OFF);
  f16* g_w1    = (f16*)(ws + W1_OFF);
  f16* g_w2    = (f16*)(ws + W2_OFF);
  f16* g_u0    = (f16*)(ws + U0_OFF);
  f16* g_u1    = (f16*)(ws + U1_OFF);
  f16* g_u2    = (f16*)(ws + U2_OFF);
  f16* g_wfc   = (f16*)(ws + WFC_OFF);
  int* g_offs  = (int*)(ws + OFFS_OFF);
  f16* g_hx    = (f16*)(ws + HX_OFF);
  u32* g_flags = (u32*)(ws + FLAGS_OFF);

  // k_rec needs 147 KB dynamic LDS
  const int REC_LDS = (65536 + 8192 + 1536) * 2;
  hipFuncSetAttribute((const void*)k_rec, hipFuncAttributeMaxDynamicSharedMemorySize, REC_LDS);

  hipLaunchKernelGGL(k_offs, dim3(1), dim3(64), 0, stream, lens, g_offs);

  auto cvt = [&](const float* s, f16* d, int n) {
    hipLaunchKernelGGL(k_cvt, dim3((n + 255) / 256), dim3(256), 0, stream, s, d, n);
  };
  cvt(w1, g_w1, 1024 * 1024);
  cvt(w2, g_w2, 1024 * 1024);
  cvt(u0, g_u0, 1024 * 512);
  cvt(u1, g_u1, 1024 * 512);
  cvt(u2, g_u2, 1024 * 512);
  cvt(wfc, g_wfc, 72 * 1024);
  hipLaunchKernelGGL(k_w0pad, dim3((1024 * 96 + 255) / 256), dim3(256), 0, stream, w0, g_w0p);
  hipLaunchKernelGGL(k_xb0, dim3((128 * 500 * 96 + 255) / 256), dim3(256), 0, stream, batch, g_xb0);
  // zero flags (ws is re-poisoned before every timed launch); monotone layer tags
  hipLaunchKernelGGL(k_zero, dim3(1), dim3(256), 0, stream, g_flags, 256);

  // layer 0
  hipLaunchKernelGGL((k_gates<0>), dim3(500, 8), dim3(256), 0, stream, g_xb0, g_w0p, b0, g_gates);
  hipLaunchKernelGGL(k_rec, dim3(64), dim3(256), REC_LDS, stream,
                     g_gates, g_u0, g_hs, g_hx, g_flags, 0);
  // layer 1
  hipLaunchKernelGGL((k_gates<1>), dim3(500, 8), dim3(256), 0, stream, g_hs, g_w1, b1, g_gates);
  hipLaunchKernelGGL(k_rec, dim3(64), dim3(256), REC_LDS, stream,
                     g_gates, g_u1, g_hs, g_hx, g_flags, 512);
  // layer 2
  hipLaunchKernelGGL((k_gates<1>), dim3(500, 8), dim3(256), 0, stream, g_hs, g_w2, b2, g_gates);
  hipLaunchKernelGGL(k_rec, dim3(64), dim3(256), REC_LDS, stream,
                     g_gates, g_u2, g_hs, g_hx, g_flags, 1024);

  // FC + pack
  hipLaunchKernelGGL(k_fc, dim3(64, 32), dim3(256), 0, stream, g_hs, g_wfc, bfc, lens, g_offs, out);
}